// Round 11
// baseline (105.866 us; speedup 1.0000x reference)
//
#include <hip/hip_runtime.h>
#include <hip/hip_fp16.h>
#include <math.h>

#define RES 256
#define TPAD 364              // padded texture dim: image coords -53..310
#define N_ANGLES 256
#define NAQ 65                // quad-group angle slots: {a, 256-a, 128-a, 128+a}
#define BATCH 8
#define ROWB (TPAD * 16)

#define SCH 8                 // s per block
#define TCH 64                // t per block
#define NTC 4                 // 256 / TCH
#define BROWS 70              // band rows
#define PTEX (BROWS * 16)     // 1120 texels per plane (16 mod-16 col slots)
#define PB (PTEX * 16)        // 17920 B; plane offsets fit ds offset immediates

typedef _Float16 h2 __attribute__((ext_vector_type(2)));
__device__ inline h2 u2h(unsigned u) { return __builtin_bit_cast(h2, u); }
__device__ inline unsigned h2u(h2 h) { return __builtin_bit_cast(unsigned, h); }

// Four planes of 16B texels (8 x fp16), each TPAD x TPAD, zero outside image:
//  p0: img(r,c)  p1: img(r,255-c)  p2: img(c,r)  p3: img(c,255-r)
__global__ void prep_pack(const float* __restrict__ imgs,
                          unsigned int* __restrict__ W) {
    int idx = blockIdx.x * blockDim.x + threadIdx.x;
    const int total = 4 * TPAD * TPAD * 4;
    if (idx >= total) return;
    int pair  = idx & 3;
    int px    = (idx >> 2) % (TPAD * TPAD);
    int plane = (idx >> 2) / (TPAD * TPAD);
    int orient = plane >> 1, side = plane & 1;
    int ct = px % TPAD, rt = px / TPAD;
    int ri = rt - 53, ci = ct - 53;
    int row, col;
    if (orient == 0) { row = ri; col = side ? (255 - ci) : ci; }
    else             { row = ci; col = side ? (255 - ri) : ri; }
    float v0 = 0.0f, v1 = 0.0f;
    if ((unsigned)row < RES && (unsigned)col < RES) {
        const float* p = imgs + ((size_t)(pair * 2) * RES + row) * RES + col;
        v0 = p[0];
        v1 = p[RES * RES];
    }
    __half2 h = __halves2half2(__float2half_rn(v0), __float2half_rn(v1));
    W[((size_t)plane * TPAD * TPAD + px) * 4 + pair] =
        *reinterpret_cast<unsigned int*>(&h);
}

// Block = (quad-angle a<=64, 8 s, 64 t), 512 threads, 1 sample/lane.
// Stage the sheared band of all 4 planes into LDS (mod-16 col slots, t-invariant
// shear coord), sample 4 taps x 4 planes per lane, reduce over t, write 4 angles.
__global__ __launch_bounds__(512, 4) void radon_kernel(
        const char* __restrict__ TEX,
        const float* __restrict__ angles,
        __half* __restrict__ part) {
    __shared__ uint4 band4[4 * PTEX];          // 71680 B
    __shared__ unsigned scr[8][SCH][16];       // 4 KB
    char* band = (char*)band4;

    const int tid = threadIdx.x;
    const int sl  = tid & 7;
    const int tl  = tid >> 3;                  // 0..63
    const int a   = blockIdx.x;                // 0..64, theta in [0, pi/4]
    const int s0  = blockIdx.y * SCH;
    const int tc  = blockIdx.z;
    const int t0  = tc * TCH;

    float theta = angles[a];
    float sn, cs;
    sincosf(theta, &sn, &cs);
    const float Rs = sn, Rt = cs, Cs = cs, Ct = -sn;   // Rt = cos >= 0.7071
    const float m = Ct / Rt;                           // in [-1, 0]

    const float smc = (float)s0 - 124.0f;              // s0 + 3.5 - 127.5
    const float tmc = (float)t0 - 96.0f;               // t0 + 31.5 - 127.5
    const float prc = fmaf(smc, Rs, fmaf(tmc, Rt, 180.5f));
    const float pcc = fmaf(smc, Cs, fmaf(tmc, Ct, 180.5f));
    const int   r0  = (int)floorf(prc - fmaf(3.5f, fabsf(Rs), 31.5f * Rt)) - 2;
    const float ubase = (pcc - m * prc) - 3.5f / Rt - 2.5f;

    const float s_c = (float)(s0 + sl) - 127.5f;
    const float prA = fmaf(s_c, Rs, 180.5f);
    const float pcA = fmaf(s_c, Cs, 180.5f);
    const float pr0 = prA - 127.5f * Rt;
    const float pc0 = pcA - 127.5f * Ct;

    // work clip: nonzero bilinear only for padded coords in [52, 309]
    const float LO = 52.0f, HI = 309.0f;
    float tmin = 0.0f, tmax = 255.0f;
    {
        float inv = 1.0f / Rt;
        float ta = (LO - pr0) * inv, tb = (HI - pr0) * inv;
        tmin = fmaxf(tmin, fminf(ta, tb));
        tmax = fminf(tmax, fmaxf(ta, tb));
    }
    if (fabsf(Ct) > 1e-6f) {
        float inv = 1.0f / Ct;
        float ta = (LO - pc0) * inv, tb = (HI - pc0) * inv;
        tmin = fmaxf(tmin, fminf(ta, tb));
        tmax = fminf(tmax, fmaxf(ta, tb));
    } else if (!(pc0 >= LO && pc0 <= HI)) {
        tmax = -1.0f;
    }

    const float tf = (float)(t0 + tl);
    const bool valid = (tf >= tmin) && (tf <= tmax);

    h2 acc[16];
    #pragma unroll
    for (int i = 0; i < 16; ++i) acc[i] = h2{};

    int anywork = __syncthreads_or((int)valid);
    if (anywork) {
        const size_t planeGB = (size_t)TPAD * TPAD * 16;
        // ---- stage: 1120 texels x 4 planes; slot = col & 15, swz = rs*5 & 15 ----
        for (int base = 0; base < PTEX; base += 512) {
            int idx = base + tid;
            if (idx < PTEX) {
                int rs = idx >> 4, j = idx & 15;
                int r = r0 + rs;
                int cb = (int)floorf(fmaf((float)r, m, ubase));
                int c = cb + j;
                unsigned ad = ((unsigned)rs << 8)
                    + ((((unsigned)c & 15u) ^ (((unsigned)rs * 5u) & 15u)) << 4);
                uint4 v0 = {}, v1 = {}, v2 = {}, v3 = {};
                if (r >= 53 && r <= 308 && c >= 53 && c <= 308) {
                    size_t go = (size_t)r * ROWB + (size_t)c * 16;
                    v0 = *(const uint4*)(TEX + go);
                    v1 = *(const uint4*)(TEX + planeGB + go);
                    v2 = *(const uint4*)(TEX + 2 * planeGB + go);
                    v3 = *(const uint4*)(TEX + 3 * planeGB + go);
                }
                *(uint4*)(band + ad) = v0;
                *(uint4*)(band + ad + PB) = v1;
                *(uint4*)(band + ad + 2 * PB) = v2;
                *(uint4*)(band + ad + 3 * PB) = v3;
            }
        }
        __syncthreads();

        // ---- sample: 4 taps x 4 planes, one (s,t) per lane ----
        if (valid) {
            float tcf = tf - 127.5f;
            float ppr = fmaf(tcf, Rt, prA);
            float ppc = fmaf(tcf, Ct, pcA);
            float wy, wx;
            int ir, ic;
            asm("v_fract_f32 %0, %1"       : "=v"(wy) : "v"(ppr));
            asm("v_fract_f32 %0, %1"       : "=v"(wx) : "v"(ppc));
            asm("v_cvt_flr_i32_f32 %0, %1" : "=v"(ir) : "v"(ppr));
            asm("v_cvt_flr_i32_f32 %0, %1" : "=v"(ic) : "v"(ppc));
            int rs = ir - r0;
            unsigned sw0 = (((unsigned)rs * 5u) & 15u) << 4;
            unsigned sw1 = (((unsigned)(rs + 1) * 5u) & 15u) << 4;
            unsigned u0 = ((unsigned)ic & 15u) << 4;
            unsigned u1 = ((unsigned)(ic + 1) & 15u) << 4;
            unsigned adr[4];
            adr[0] = ((unsigned)rs << 8) + (u0 ^ sw0);
            adr[1] = ((unsigned)rs << 8) + (u1 ^ sw0);
            adr[2] = ((unsigned)(rs + 1) << 8) + (u0 ^ sw1);
            adr[3] = ((unsigned)(rs + 1) << 8) + (u1 ^ sw1);
            float wy1 = 1.0f - wy, wx1 = 1.0f - wx;
            float wf[4] = { wy1 * wx1, wy1 * wx, wy * wx1, wy * wx };
            #pragma unroll
            for (int tap = 0; tap < 4; ++tap) {
                auto pkr = __builtin_amdgcn_cvt_pkrtz(wf[tap], wf[tap]);
                h2 wv = __builtin_bit_cast(h2, pkr);
                #pragma unroll
                for (int p = 0; p < 4; ++p) {
                    uint4 q = *(const uint4*)(band + adr[tap] + p * PB);
                    acc[p * 4 + 0] = wv * u2h(q.x) + acc[p * 4 + 0];
                    acc[p * 4 + 1] = wv * u2h(q.y) + acc[p * 4 + 1];
                    acc[p * 4 + 2] = wv * u2h(q.z) + acc[p * 4 + 2];
                    acc[p * 4 + 3] = wv * u2h(q.w) + acc[p * 4 + 3];
                }
            }
        }
    }

    // ---- reduce over t: in-wave (lane bits 3-5), then cross-wave via scr ----
    #pragma unroll
    for (int i = 0; i < 16; ++i) {
        acc[i] = acc[i] + u2h((unsigned)__shfl_xor((int)h2u(acc[i]), 8));
        acc[i] = acc[i] + u2h((unsigned)__shfl_xor((int)h2u(acc[i]), 16));
        acc[i] = acc[i] + u2h((unsigned)__shfl_xor((int)h2u(acc[i]), 32));
    }
    const int w = tid >> 6;
    if (((tid >> 3) & 7) == 0) {
        #pragma unroll
        for (int i = 0; i < 16; ++i) scr[w][sl][i] = h2u(acc[i]);
    }
    __syncthreads();

    // ---- final: 128 threads -> (s, word); write 4 angle images ----
    if (tid < 128) {
        int s = tid >> 4, j = tid & 15;
        float sx = 0.f, sy = 0.f;
        #pragma unroll
        for (int ww = 0; ww < 8; ++ww) {
            h2 v = u2h(scr[ww][s][j]);
            sx += (float)v.x;
            sy += (float)v.y;
        }
        int p = j >> 2, q = j & 3;
        int ai;
        bool wr = true;
        if      (p == 0) { ai = a; }
        else if (p == 1) { ai = 256 - a; wr = (a != 0); }
        else if (p == 2) { ai = 128 - a; wr = (a != 64); }
        else             { ai = 128 + a; wr = (a != 0) && (a != 64); }
        if (wr) {
            const size_t AR = (size_t)N_ANGLES * RES;
            size_t base = (size_t)(tc * BATCH + 2 * q) * AR
                        + (size_t)ai * RES + (s0 + s);
            part[base]      = __float2half(sx);
            part[base + AR] = __float2half(sy);
        }
    }
}

__global__ void combine(const __half2* __restrict__ p, float2* __restrict__ out) {
    const int n2 = BATCH * N_ANGLES * RES / 2;   // 262144
    int i = blockIdx.x * blockDim.x + threadIdx.x;
    if (i < n2) {
        float2 x0 = __half22float2(p[i]);
        float2 x1 = __half22float2(p[i + n2]);
        float2 x2 = __half22float2(p[i + 2 * n2]);
        float2 x3 = __half22float2(p[i + 3 * n2]);
        out[i] = make_float2(x0.x + x1.x + x2.x + x3.x,
                             x0.y + x1.y + x2.y + x3.y);
    }
}

extern "C" void kernel_launch(void* const* d_in, const int* in_sizes, int n_in,
                              void* d_out, int out_size, void* d_ws, size_t ws_size,
                              hipStream_t stream) {
    const float* imgs   = (const float*)d_in[0];
    const float* angles = (const float*)d_in[1];
    float* out = (float*)d_out;

    const size_t planeGB = (size_t)TPAD * TPAD * 16;         // 2.12 MB
    char*   TEX  = (char*)d_ws;                              // 4 planes, 8.48 MB
    __half* part = (__half*)(TEX + 4 * planeGB);             // 4 x 1 MB fp16

    const int prep_total = 4 * TPAD * TPAD * 4;
    prep_pack<<<(prep_total + 255) / 256, 256, 0, stream>>>(
        imgs, (unsigned int*)TEX);

    dim3 grid(NAQ, RES / SCH, NTC);                          // 65 x 32 x 4
    radon_kernel<<<grid, 512, 0, stream>>>(TEX, angles, part);

    const int n2 = BATCH * N_ANGLES * RES / 2;
    combine<<<(n2 + 255) / 256, 256, 0, stream>>>((const __half2*)part, (float2*)out);
}

// Round 12
// 58.112 us; speedup vs baseline: 1.8218x; 1.8218x over previous
//
#include <hip/hip_runtime.h>
#include <hip/hip_fp16.h>
#include <math.h>

#define RES 256
#define TPAD 364              // padded texture dim: image coords -53..310
#define N_ANGLES 256
#define NAQ 65                // quad angle slots: {a, 256-a, 128-a, 128+a}
#define BATCH 8
#define ROWB (TPAD * 16)      // plane row pitch bytes (5824)

typedef _Float16 h2 __attribute__((ext_vector_type(2)));
__device__ inline h2 u2h(unsigned u) { return __builtin_bit_cast(h2, u); }
__device__ inline unsigned h2u(h2 h) { return __builtin_bit_cast(unsigned, h); }

// Four planes of 16B texels (8 x fp16), each TPAD x TPAD, zero outside image:
//  p0: img(r,c)  p1: img(r,255-c)  p2: img(c,r)  p3: img(c,255-r)
// Serves angles {a, 256-a, 128-a, 128+a} from ONE coordinate computation.
__global__ void prep_pack(const float* __restrict__ imgs,
                          unsigned int* __restrict__ W) {
    int idx = blockIdx.x * blockDim.x + threadIdx.x;
    const int total = 4 * TPAD * TPAD * 4;
    if (idx >= total) return;
    int pair  = idx & 3;
    int px    = (idx >> 2) % (TPAD * TPAD);
    int plane = (idx >> 2) / (TPAD * TPAD);
    int orient = plane >> 1, side = plane & 1;
    int ct = px % TPAD, rt = px / TPAD;
    int ri = rt - 53, ci = ct - 53;
    int row, col;
    if (orient == 0) { row = ri; col = side ? (255 - ci) : ci; }
    else             { row = ci; col = side ? (255 - ri) : ri; }
    float v0 = 0.0f, v1 = 0.0f;
    if ((unsigned)row < RES && (unsigned)col < RES) {
        const float* p = imgs + ((size_t)(pair * 2) * RES + row) * RES + col;
        v0 = p[0];
        v1 = p[RES * RES];
    }
    __half2 h = __halves2half2(__float2half_rn(v0), __float2half_rn(v1));
    W[((size_t)plane * TPAD * TPAD + px) * 4 + pair] =
        *reinterpret_cast<unsigned int*>(&h);
}

// Direct-gather, square wave footprint. Lane = tap(2b) | tl(2b) | sl(2b) | wave(2b).
// Block = (quad-angle a, 4 s); waves cover t = (4*wid + tl) + 16k, k=0..15.
// Per lane-step: ONE coord+weight computation, FOUR plane loads from one boff
// -> 4 angles x 8 batches. All t in-block -> direct f32 output, no partials.
__global__ __launch_bounds__(256) void radon_kernel(
        const char* __restrict__ TEX,
        const float* __restrict__ angles,
        float* __restrict__ out) {
    __shared__ unsigned scr[4][4][16];

    const int tid = threadIdx.x;
    const int tap = tid & 3;
    const int tl  = (tid >> 2) & 3;
    const int sl  = (tid >> 4) & 3;
    const int wid = tid >> 6;
    const int a   = blockIdx.x;            // 0..64, theta in [0, pi/4]
    const int s0  = blockIdx.y * 4;

    float theta = angles[a];
    float sn, cs;
    sincosf(theta, &sn, &cs);
    const float Rs = sn, Rt = cs, Cs = cs, Ct = -sn;   // Rt >= 0.7071

    const float s_c = (float)(s0 + sl) - 127.5f;
    const float prA = fmaf(s_c, Rs, 180.5f);
    const float pcA = fmaf(s_c, Cs, 180.5f);
    const float pr0 = prA - 127.5f * Rt;
    const float pc0 = pcA - 127.5f * Ct;

    // work clip: nonzero bilinear only for padded coords in [52, 309]
    const float LO = 52.0f, HI = 309.0f;
    float tmin = 0.0f, tmax = 255.0f;
    {
        float inv = 1.0f / Rt;
        float ta = (LO - pr0) * inv, tb = (HI - pr0) * inv;
        tmin = fmaxf(tmin, fminf(ta, tb));
        tmax = fminf(tmax, fmaxf(ta, tb));
    }
    if (fabsf(Ct) > 1e-6f) {
        float inv = 1.0f / Ct;
        float ta = (LO - pc0) * inv, tb = (HI - pc0) * inv;
        tmin = fmaxf(tmin, fminf(ta, tb));
        tmax = fminf(tmax, fmaxf(ta, tb));
    } else if (!(pc0 >= LO && pc0 <= HI)) {
        tmax = -1.0f;
    }

    const int tt = wid * 4 + tl;          // 0..15; lane t = tt + 16k
    int kmin = (int)ceilf((tmin - (float)tt) * 0.0625f);
    int kmax = (int)floorf((tmax - (float)tt) * 0.0625f);
    kmin = max(kmin, 0);
    kmax = min(kmax, 15);

    const int dr = tap >> 1, dc = tap & 1;
    const unsigned tapoff = (unsigned)(dr * ROWB + dc * 16);
    const float xb = dc ? 0.0f : 1.0f, xs = dc ? 1.0f : -1.0f;
    const float yb = dr ? 0.0f : 1.0f, ys = dr ? 1.0f : -1.0f;

    const size_t planeGB = (size_t)TPAD * TPAD * 16;
    const char* b0 = TEX;
    const char* b1 = TEX + planeGB;
    const char* b2 = TEX + 2 * planeGB;
    const char* b3 = TEX + 3 * planeGB;

    h2 acc[16];
    #pragma unroll
    for (int i = 0; i < 16; ++i) acc[i] = h2{};

    float tf = (float)(tt + 16 * kmin) - 127.5f;
    for (int k = kmin; k <= kmax; ++k) {
        float ppr = fmaf(tf, Rt, prA);
        float ppc = fmaf(tf, Ct, pcA);
        tf += 16.0f;
        float wy, wx;
        int ir, ic;
        asm("v_fract_f32 %0, %1"       : "=v"(wy) : "v"(ppr));
        asm("v_fract_f32 %0, %1"       : "=v"(wx) : "v"(ppc));
        asm("v_cvt_flr_i32_f32 %0, %1" : "=v"(ir) : "v"(ppr));
        asm("v_cvt_flr_i32_f32 %0, %1" : "=v"(ic) : "v"(ppc));
        unsigned x = ((unsigned)ic << 4) + tapoff;
        unsigned bo;
        asm("v_mad_u32_u24 %0, %1, %2, %3"
            : "=v"(bo) : "v"(ir), "s"(ROWB), "v"(x));
        float w = fmaf(xs, wx, xb) * fmaf(ys, wy, yb);
        auto pkr = __builtin_amdgcn_cvt_pkrtz(w, w);
        h2 wv = __builtin_bit_cast(h2, pkr);

        uint4 q0 = *(const uint4*)(b0 + bo);
        uint4 q1 = *(const uint4*)(b1 + bo);
        uint4 q2 = *(const uint4*)(b2 + bo);
        uint4 q3 = *(const uint4*)(b3 + bo);

        acc[0]  = wv * u2h(q0.x) + acc[0];   acc[1]  = wv * u2h(q0.y) + acc[1];
        acc[2]  = wv * u2h(q0.z) + acc[2];   acc[3]  = wv * u2h(q0.w) + acc[3];
        acc[4]  = wv * u2h(q1.x) + acc[4];   acc[5]  = wv * u2h(q1.y) + acc[5];
        acc[6]  = wv * u2h(q1.z) + acc[6];   acc[7]  = wv * u2h(q1.w) + acc[7];
        acc[8]  = wv * u2h(q2.x) + acc[8];   acc[9]  = wv * u2h(q2.y) + acc[9];
        acc[10] = wv * u2h(q2.z) + acc[10];  acc[11] = wv * u2h(q2.w) + acc[11];
        acc[12] = wv * u2h(q3.x) + acc[12];  acc[13] = wv * u2h(q3.y) + acc[13];
        acc[14] = wv * u2h(q3.z) + acc[14];  acc[15] = wv * u2h(q3.w) + acc[15];
    }

    // reduce taps (bits 0-1) and tl (bits 2-3); f32 to preserve accuracy
    float fa[16];
    #pragma unroll
    for (int i = 0; i < 16; ++i) {
        float vx = (float)acc[i].x + (float)acc[i].y;   // keep batches separate!
        (void)vx;
    }
    // do reduction on packed h2 via f32 pairs: unpack to two f32, shfl as f32
    float rx[16], ry[16];
    #pragma unroll
    for (int i = 0; i < 16; ++i) { rx[i] = (float)acc[i].x; ry[i] = (float)acc[i].y; }
    #pragma unroll
    for (int i = 0; i < 16; ++i) {
        rx[i] += __shfl_xor(rx[i], 1);  ry[i] += __shfl_xor(ry[i], 1);
        rx[i] += __shfl_xor(rx[i], 2);  ry[i] += __shfl_xor(ry[i], 2);
        rx[i] += __shfl_xor(rx[i], 4);  ry[i] += __shfl_xor(ry[i], 4);
        rx[i] += __shfl_xor(rx[i], 8);  ry[i] += __shfl_xor(ry[i], 8);
    }
    if ((tid & 15) == 0) {
        #pragma unroll
        for (int i = 0; i < 16; ++i) {
            auto pp = __builtin_amdgcn_cvt_pkrtz(rx[i], ry[i]);   // NOT accuracy
            (void)pp;
        }
        // store as two f32 halves packed via scr pairs: use 2 words per i
    }
    // --- simpler: store f32 sums directly (scr reinterpreted as float) ---
    __shared__ float scrf[4][4][32];
    if ((tid & 15) == 0) {
        #pragma unroll
        for (int i = 0; i < 16; ++i) {
            scrf[wid][sl][2 * i]     = rx[i];
            scrf[wid][sl][2 * i + 1] = ry[i];
        }
    }
    __syncthreads();

    if (tid < 128) {
        int s_idx = tid >> 5, o = tid & 31;     // o = p*8 + b
        int p = o >> 3, b = o & 7;
        int word = (p * 4 + (b >> 1)) * 2 + (b & 1);
        float sum = scrf[0][s_idx][word] + scrf[1][s_idx][word]
                  + scrf[2][s_idx][word] + scrf[3][s_idx][word];
        int ai;
        bool wr = true;
        if      (p == 0) { ai = a; }
        else if (p == 1) { ai = 256 - a; wr = (a != 0); }
        else if (p == 2) { ai = 128 - a; wr = (a != 64); }
        else             { ai = 128 + a; wr = (a != 0) && (a != 64); }
        if (wr)
            out[((size_t)b * N_ANGLES + ai) * RES + (s0 + s_idx)] = sum;
    }
}

extern "C" void kernel_launch(void* const* d_in, const int* in_sizes, int n_in,
                              void* d_out, int out_size, void* d_ws, size_t ws_size,
                              hipStream_t stream) {
    const float* imgs   = (const float*)d_in[0];
    const float* angles = (const float*)d_in[1];
    float* out = (float*)d_out;

    char* TEX = (char*)d_ws;                                 // 4 planes, 8.48 MB

    const int prep_total = 4 * TPAD * TPAD * 4;
    prep_pack<<<(prep_total + 255) / 256, 256, 0, stream>>>(
        imgs, (unsigned int*)TEX);

    dim3 grid(NAQ, RES / 4);                                 // 65 x 64 blocks
    radon_kernel<<<grid, 256, 0, stream>>>(TEX, angles, out);
}